// Round 2
// baseline (946.417 us; speedup 1.0000x reference)
//
#include <hip/hip_runtime.h>

#define C_ 256
#define T_ 16
#define H_ 64
#define W_ 64
#define PT 5
#define PH 8
#define PW 8
#define OT 4
#define OH 7
#define OW 7
#define SSCALE (1.0f/16.0f)
#define TSCALE 1.0f
#define CG 32               /* channels per roi block */
#define LROW 66             /* smp row stride: even (8B-align f2v) and 66%32==2 -> 2-way max */

typedef float f4v __attribute__((ext_vector_type(4)));
typedef float f2v __attribute__((ext_vector_type(2)));

// ---------------- transpose (B,C,T,H,W) -> (B,T,H,W,C) ----------------
__global__ __launch_bounds__(256) void transpose_kernel(const float* __restrict__ f,
                                                        float* __restrict__ ft) {
    __shared__ float tile[64][65];
    const int THW = T_ * H_ * W_;
    int thw0 = blockIdx.x * 64;
    int c0 = blockIdx.y * 64;
    int b = blockIdx.z;
    int l4 = threadIdx.x & 15;
    int row = threadIdx.x >> 4;
#pragma unroll
    for (int k = 0; k < 4; ++k) {
        int c = row + k * 16;
        const f4v* src = reinterpret_cast<const f4v*>(
            &f[((size_t)b * C_ + c0 + c) * THW + thw0 + l4 * 4]);
        f4v v = __builtin_nontemporal_load(src);
        tile[c][l4 * 4 + 0] = v[0];
        tile[c][l4 * 4 + 1] = v[1];
        tile[c][l4 * 4 + 2] = v[2];
        tile[c][l4 * 4 + 3] = v[3];
    }
    __syncthreads();
#pragma unroll
    for (int k = 0; k < 4; ++k) {
        int t = row + k * 16;
        f4v v;
        v[0] = tile[l4 * 4 + 0][t];
        v[1] = tile[l4 * 4 + 1][t];
        v[2] = tile[l4 * 4 + 2][t];
        v[3] = tile[l4 * 4 + 3][t];
        *reinterpret_cast<f4v*>(&ft[((size_t)b * THW + thw0 + t) * C_ + c0 + l4 * 4]) = v;
    }
}

// ---------------- main: one block per (roi, 32-channel group) ----------------
// t-plane streaming: compute sample plane t (8x8 x 32ch) into smp[t&1],
// pool t_out = t-1 from planes (t-1, t). LDS ~17 KB -> high occupancy.
__global__ __launch_bounds__(256, 6) void roi_kernel(const float* __restrict__ ft,
                                                     const float* __restrict__ rois,
                                                     float* __restrict__ out) {
    __shared__ float smp[2][CG][LROW];   // 16896 B
    __shared__ float sroi[7];
    __shared__ int2 s_trow[PT]; __shared__ float2 s_twt[PT];
    __shared__ int2 s_yrow[PH]; __shared__ float2 s_ywt[PH];
    __shared__ int2 s_xoff[PW]; __shared__ float2 s_xwt[PW];

    int r = blockIdx.y;
    int c0 = blockIdx.x * CG;

    if (threadIdx.x < 7) sroi[threadIdx.x] = rois[r * 7 + threadIdx.x];
    __syncthreads();

    // axis tables: byte offsets (lo/hi) + validity-folded weights, per axis sample
    if (threadIdx.x < 21) {
        int i = threadIdx.x;
        float start, end, size;
        int j, n, scale;
        if (i < 5) {
            j = i; n = PT;
            start = sroi[5] * TSCALE; end = sroi[6] * TSCALE;
            size = (float)T_; scale = H_ * W_ * C_ * 4;
        } else if (i < 13) {
            j = i - 5; n = PH;
            start = sroi[2] * SSCALE; end = sroi[4] * SSCALE;
            size = (float)H_; scale = W_ * C_ * 4;
        } else {
            j = i - 13; n = PW;
            start = sroi[1] * SSCALE; end = sroi[3] * SSCALE;
            size = (float)W_; scale = C_ * 4;
        }
        float length = fmaxf(end - start + 1.0f, 1.0f);
        float step = length / (float)(n - 1);
        float coord = start + step * (float)j;
        float valid = (coord >= 0.0f && coord < size) ? 1.0f : 0.0f;
        float lo = fminf(fmaxf(floorf(coord), 0.0f), size - 1.0f);
        int lo_i = (int)lo;
        int hi_i = min(lo_i + 1, (int)size - 1);
        float fr = coord - lo;
        int2 offs; offs.x = lo_i * scale; offs.y = hi_i * scale;
        float2 wts; wts.x = (1.0f - fr) * valid; wts.y = fr * valid;
        if (i < 5)       { s_trow[j] = offs; s_twt[j] = wts; }
        else if (i < 13) { s_yrow[j] = offs; s_ywt[j] = wts; }
        else             { s_xoff[j] = offs; s_xwt[j] = wts; }
    }
    __syncthreads();

    int b = (int)sroi[0];
    int c4 = threadIdx.x & 7;     // float4 lane within 32-channel group
    int slot = threadIdx.x >> 3;  // 0..31 sample slot
    const char* fb = (const char*)ft
        + ((size_t)b * (T_ * H_ * W_ * C_) + (size_t)(c0 + c4 * 4)) * 4;

    for (int t = 0; t < PT; ++t) {
        // ---- compute plane t: 64 samples x 32 channels ----
        int2 tr = s_trow[t];
        float2 tw = s_twt[t];
        float (*buf)[LROW] = smp[t & 1];
#pragma unroll
        for (int k = 0; k < 2; ++k) {
            int yx = slot + k * 32;
            int y = yx >> 3, x = yx & 7;
            int2 yr = s_yrow[y]; float2 yw = s_ywt[y];
            int2 xo = s_xoff[x]; float2 xw = s_xwt[x];
            int rA = tr.x + yr.x;
            int rB = tr.x + yr.y;
            int rC = tr.y + yr.x;
            int rD = tr.y + yr.y;
            float wA = tw.x * yw.x, wB = tw.x * yw.y;
            float wC = tw.y * yw.x, wD = tw.y * yw.y;
            f4v a0 = *(const f4v*)(fb + rA + xo.x);
            f4v a1 = *(const f4v*)(fb + rA + xo.y);
            f4v b0 = *(const f4v*)(fb + rB + xo.x);
            f4v b1 = *(const f4v*)(fb + rB + xo.y);
            f4v e0 = *(const f4v*)(fb + rC + xo.x);
            f4v e1 = *(const f4v*)(fb + rC + xo.y);
            f4v d0 = *(const f4v*)(fb + rD + xo.x);
            f4v d1 = *(const f4v*)(fb + rD + xo.y);
            f4v vl = wA * a0 + wB * b0 + wC * e0 + wD * d0;
            f4v vh = wA * a1 + wB * b1 + wC * e1 + wD * d1;
            f4v v = xw.x * vl + xw.y * vh;
            float* col = &buf[c4 * 4][yx];
            col[0 * LROW] = v[0];
            col[1 * LROW] = v[1];
            col[2 * LROW] = v[2];
            col[3 * LROW] = v[3];
        }
        __syncthreads();

        // ---- pool t_out = t-1 from planes (t-1, t) ----
        if (t > 0) {
            int cc = threadIdx.x & 31;
            int hh = threadIdx.x >> 5;   // 0..7, h row; hh==7 idle
            if (hh < 7) {
                const float* pa = &smp[(t - 1) & 1][cc][hh * 8];
                const float* pb = &smp[t & 1][cc][hh * 8];
                float s8[8];
#pragma unroll
                for (int x2 = 0; x2 < 4; ++x2) {
                    f2v alo = *(const f2v*)(pa + 2 * x2);
                    f2v ahi = *(const f2v*)(pa + 8 + 2 * x2);
                    f2v blo = *(const f2v*)(pb + 2 * x2);
                    f2v bhi = *(const f2v*)(pb + 8 + 2 * x2);
                    f2v s = (alo + ahi) + (blo + bhi);
                    s8[2 * x2] = s[0];
                    s8[2 * x2 + 1] = s[1];
                }
                float* op = out + ((size_t)r * C_ + c0 + cc) * (OT * OH * OW)
                          + (t - 1) * (OH * OW) + hh * OW;
#pragma unroll
                for (int w = 0; w < 7; ++w)
                    __builtin_nontemporal_store((s8[w] + s8[w + 1]) * 0.125f, op + w);
            }
        }
        __syncthreads();
    }
}

// ---------------- fallback: direct gather, one thread per output ----------------
__device__ __forceinline__ void axis_sample(float start, float end, float size, int n,
                                            int j, int& lo_i, int& hi_i, float& frac,
                                            float& valid) {
    float length = fmaxf(end - start + 1.0f, 1.0f);
    float step = length / (float)(n - 1);
    float coord = start + step * (float)j;
    valid = (coord >= 0.0f && coord < size) ? 1.0f : 0.0f;
    float lo = fminf(fmaxf(floorf(coord), 0.0f), size - 1.0f);
    frac = coord - lo;
    lo_i = (int)lo;
    hi_i = min(lo_i + 1, (int)size - 1);
}

__global__ void roi_direct(const float* __restrict__ f, const float* __restrict__ rois,
                           float* __restrict__ out, long long total) {
    long long idx = (long long)blockIdx.x * 256 + threadIdx.x;
    if (idx >= total) return;
    int w = (int)(idx % OW);
    long long q = idx / OW;
    int h = (int)(q % OH);
    q /= OH;
    int t = (int)(q % OT);
    q /= OT;
    int c = (int)(q % C_);
    int r = (int)(q / C_);

    float rb = rois[r * 7 + 0];
    float x1 = rois[r * 7 + 1] * SSCALE;
    float y1 = rois[r * 7 + 2] * SSCALE;
    float x2 = rois[r * 7 + 3] * SSCALE;
    float y2 = rois[r * 7 + 4] * SSCALE;
    float t1 = rois[r * 7 + 5] * TSCALE;
    float t2 = rois[r * 7 + 6] * TSCALE;
    int b = (int)rb;
    const float* fc = f + ((size_t)b * C_ + c) * (T_ * H_ * W_);

    float acc = 0.0f;
    for (int dt = 0; dt < 2; ++dt) {
        int tlo, thi; float tf, tv;
        axis_sample(t1, t2, (float)T_, PT, t + dt, tlo, thi, tf, tv);
        for (int dh = 0; dh < 2; ++dh) {
            int ylo, yhi; float yf, yv;
            axis_sample(y1, y2, (float)H_, PH, h + dh, ylo, yhi, yf, yv);
            for (int dw = 0; dw < 2; ++dw) {
                int xlo, xhi; float xf, xv;
                axis_sample(x1, x2, (float)W_, PW, w + dw, xlo, xhi, xf, xv);
                float v000 = fc[(tlo * H_ + ylo) * W_ + xlo];
                float v001 = fc[(tlo * H_ + ylo) * W_ + xhi];
                float v010 = fc[(tlo * H_ + yhi) * W_ + xlo];
                float v011 = fc[(tlo * H_ + yhi) * W_ + xhi];
                float v100 = fc[(thi * H_ + ylo) * W_ + xlo];
                float v101 = fc[(thi * H_ + ylo) * W_ + xhi];
                float v110 = fc[(thi * H_ + yhi) * W_ + xlo];
                float v111 = fc[(thi * H_ + yhi) * W_ + xhi];
                float vx00 = v000 + xf * (v001 - v000);
                float vx01 = v010 + xf * (v011 - v010);
                float vx10 = v100 + xf * (v101 - v100);
                float vx11 = v110 + xf * (v111 - v110);
                float vy0 = vx00 + yf * (vx01 - vx00);
                float vy1 = vx10 + yf * (vx11 - vx10);
                float v = vy0 + tf * (vy1 - vy0);
                acc += v * (tv * yv * xv);
            }
        }
    }
    out[idx] = acc * 0.125f;
}

extern "C" void kernel_launch(void* const* d_in, const int* in_sizes, int n_in,
                              void* d_out, int out_size, void* d_ws, size_t ws_size,
                              hipStream_t stream) {
    const float* feat = (const float*)d_in[0];
    const float* rois = (const float*)d_in[1];
    float* out = (float*)d_out;
    int nroi = in_sizes[1] / 7;
    int B = in_sizes[0] / (C_ * T_ * H_ * W_);
    size_t need = (size_t)B * T_ * H_ * W_ * C_ * sizeof(float);

    if (ws_size >= need) {
        dim3 g1(T_ * H_ * W_ / 64, C_ / 64, B);
        transpose_kernel<<<g1, 256, 0, stream>>>(feat, (float*)d_ws);
        dim3 g2(C_ / CG, nroi);
        roi_kernel<<<g2, 256, 0, stream>>>((const float*)d_ws, rois, out);
    } else {
        long long total = (long long)nroi * C_ * OT * OH * OW;
        roi_direct<<<(int)((total + 255) / 256), 256, 0, stream>>>(feat, rois, out, total);
    }
}

// Round 3
// 626.511 us; speedup vs baseline: 1.5106x; 1.5106x over previous
//
#include <hip/hip_runtime.h>

#define C_ 256
#define T_ 16
#define H_ 64
#define W_ 64
#define PT 5
#define PH 8
#define PW 8
#define OT 4
#define OH 7
#define OW 7
#define SSCALE (1.0f/16.0f)
#define TSCALE 1.0f
#define CG 32               /* channels per roi block */
#define LROW 66             /* plane row stride: 8B-aligned, 2-way banks max */
#define NOUT (CG * OT * OH * OW)   /* 6272 outputs per block */

typedef float f4v __attribute__((ext_vector_type(4)));
typedef float f2v __attribute__((ext_vector_type(2)));

// ---------------- transpose (B,C,T,H,W) -> (B,T,H,W,C) ----------------
// 64c x 256thw per block (4 sub-tiles) -> each (b,c) row read 1KB-contiguous.
__global__ __launch_bounds__(256) void transpose_kernel(const float* __restrict__ f,
                                                        float* __restrict__ ft) {
    __shared__ float tile[64][65];
    const int THW = T_ * H_ * W_;
    int c0 = blockIdx.y * 64;
    int b = blockIdx.z;
    int l4 = threadIdx.x & 15;
    int row = threadIdx.x >> 4;
    for (int k4 = 0; k4 < 4; ++k4) {
        int thw0 = blockIdx.x * 256 + k4 * 64;
        if (k4) __syncthreads();
#pragma unroll
        for (int k = 0; k < 4; ++k) {
            int c = row + k * 16;
            const f4v* src = reinterpret_cast<const f4v*>(
                &f[((size_t)b * C_ + c0 + c) * THW + thw0 + l4 * 4]);
            f4v v = __builtin_nontemporal_load(src);  // f read once; keep L3 for ft
            tile[c][l4 * 4 + 0] = v[0];
            tile[c][l4 * 4 + 1] = v[1];
            tile[c][l4 * 4 + 2] = v[2];
            tile[c][l4 * 4 + 3] = v[3];
        }
        __syncthreads();
#pragma unroll
        for (int k = 0; k < 4; ++k) {
            int t = row + k * 16;
            f4v v;
            v[0] = tile[l4 * 4 + 0][t];
            v[1] = tile[l4 * 4 + 1][t];
            v[2] = tile[l4 * 4 + 2][t];
            v[3] = tile[l4 * 4 + 3][t];
            *reinterpret_cast<f4v*>(&ft[((size_t)b * THW + thw0 + t) * C_ + c0 + l4 * 4]) = v;
        }
    }
}

// ---------------- main: one block per (roi, 32-channel group) ----------------
// t-plane streaming + register-accumulated pool + coalesced final flush.
__global__ __launch_bounds__(256, 4) void roi_kernel(const float* __restrict__ ft,
                                                     const float* __restrict__ rois,
                                                     float* __restrict__ out) {
    __shared__ float scratch[NOUT];  // 25088 B; first 2112 floats double as plane buffer
    __shared__ float sroi[7];
    __shared__ int2 s_trow[PT]; __shared__ float2 s_twt[PT];
    __shared__ int2 s_yrow[PH]; __shared__ float2 s_ywt[PH];
    __shared__ int2 s_xoff[PW]; __shared__ float2 s_xwt[PW];

    // (roi, cgroup) decode with XCD-grouping: the 8 cgroup blocks of a roi land
    // on the same XCD (assuming round-robin bid%8 -> XCD), temporally adjacent.
    int bid = blockIdx.x;
    int r, cg;
    if ((gridDim.x & 63) == 0) {
        int xcd = bid & 7, m = bid >> 3;
        cg = m & 7;
        r = ((m >> 3) << 3) | xcd;
    } else {
        r = bid >> 3;
        cg = bid & 7;
    }
    int c0 = cg * CG;

    if (threadIdx.x < 7) sroi[threadIdx.x] = rois[r * 7 + threadIdx.x];
    __syncthreads();

    // axis tables: byte offsets (lo/hi) + validity-folded weights
    if (threadIdx.x < 21) {
        int i = threadIdx.x;
        float start, end, size;
        int j, n, scale;
        if (i < 5) {
            j = i; n = PT;
            start = sroi[5] * TSCALE; end = sroi[6] * TSCALE;
            size = (float)T_; scale = H_ * W_ * C_ * 4;
        } else if (i < 13) {
            j = i - 5; n = PH;
            start = sroi[2] * SSCALE; end = sroi[4] * SSCALE;
            size = (float)H_; scale = W_ * C_ * 4;
        } else {
            j = i - 13; n = PW;
            start = sroi[1] * SSCALE; end = sroi[3] * SSCALE;
            size = (float)W_; scale = C_ * 4;
        }
        float length = fmaxf(end - start + 1.0f, 1.0f);
        float step = length / (float)(n - 1);
        float coord = start + step * (float)j;
        float valid = (coord >= 0.0f && coord < size) ? 1.0f : 0.0f;
        float lo = fminf(fmaxf(floorf(coord), 0.0f), size - 1.0f);
        int lo_i = (int)lo;
        int hi_i = min(lo_i + 1, (int)size - 1);
        float fr = coord - lo;
        int2 offs; offs.x = lo_i * scale; offs.y = hi_i * scale;
        float2 wts; wts.x = (1.0f - fr) * valid; wts.y = fr * valid;
        if (i < 5)       { s_trow[j] = offs; s_twt[j] = wts; }
        else if (i < 13) { s_yrow[j] = offs; s_ywt[j] = wts; }
        else             { s_xoff[j] = offs; s_xwt[j] = wts; }
    }
    __syncthreads();

    int b = (int)sroi[0];
    int c4 = threadIdx.x & 7;     // float4 lane within 32-channel group
    int slot = threadIdx.x >> 3;  // 0..31 sample slot
    const char* fb = (const char*)ft
        + ((size_t)b * (T_ * H_ * W_ * C_) + (size_t)(c0 + c4 * 4)) * 4;

    float (*buf)[LROW] = (float(*)[LROW])scratch;  // 32 x 66 = 2112 floats
    int cc = threadIdx.x & 31;
    int hh = threadIdx.x >> 5;    // 0..7; hh==7 idle for pooling

    float racc[OT][OW];           // statically indexed (t-loop fully unrolled)
#pragma unroll
    for (int t = 0; t < OT; ++t)
#pragma unroll
        for (int w = 0; w < OW; ++w) racc[t][w] = 0.0f;

#pragma unroll
    for (int t = 0; t < PT; ++t) {
        if (t) __syncthreads();   // pool reads of plane t-1 done before overwrite

        // ---- compute plane t: 64 samples x 32 channels ----
        int2 tr = s_trow[t];
        float2 tw = s_twt[t];
#pragma unroll
        for (int k = 0; k < 2; ++k) {
            int yx = slot + k * 32;
            int y = yx >> 3, x = yx & 7;
            int2 yr = s_yrow[y]; float2 yw = s_ywt[y];
            int2 xo = s_xoff[x]; float2 xw = s_xwt[x];
            int rA = tr.x + yr.x;
            int rB = tr.x + yr.y;
            int rC = tr.y + yr.x;
            int rD = tr.y + yr.y;
            float wA = tw.x * yw.x, wB = tw.x * yw.y;
            float wC = tw.y * yw.x, wD = tw.y * yw.y;
            f4v a0 = *(const f4v*)(fb + rA + xo.x);
            f4v a1 = *(const f4v*)(fb + rA + xo.y);
            f4v b0 = *(const f4v*)(fb + rB + xo.x);
            f4v b1 = *(const f4v*)(fb + rB + xo.y);
            f4v e0 = *(const f4v*)(fb + rC + xo.x);
            f4v e1 = *(const f4v*)(fb + rC + xo.y);
            f4v d0 = *(const f4v*)(fb + rD + xo.x);
            f4v d1 = *(const f4v*)(fb + rD + xo.y);
            f4v vl = wA * a0 + wB * b0 + wC * e0 + wD * d0;
            f4v vh = wA * a1 + wB * b1 + wC * e1 + wD * d1;
            f4v v = xw.x * vl + xw.y * vh;
            float* col = &buf[c4 * 4][yx];
            col[0 * LROW] = v[0];
            col[1 * LROW] = v[1];
            col[2 * LROW] = v[2];
            col[3 * LROW] = v[3];
        }
        __syncthreads();

        // ---- accumulate plane t into racc[t] (dt=0) and racc[t-1] (dt=1) ----
        if (hh < 7) {
            const float* p = &buf[cc][hh * 8];
            float p2[8];
#pragma unroll
            for (int x2 = 0; x2 < 4; ++x2) {
                f2v a = *(const f2v*)(p + 2 * x2);
                f2v bq = *(const f2v*)(p + 8 + 2 * x2);
                f2v s = a + bq;           // y-pool (rows hh, hh+1)
                p2[2 * x2] = s[0];
                p2[2 * x2 + 1] = s[1];
            }
#pragma unroll
            for (int w = 0; w < OW; ++w) {
                float pw = p2[w] + p2[w + 1];   // x-pool
                if (t < OT) racc[t][w] += pw;
                if (t > 0) racc[t - 1][w] += pw;
            }
        }
    }
    __syncthreads();  // plane buffer dead; scratch reused for flush

    // ---- stage pooled outputs in (c,t,h,w) order, flush coalesced ----
    if (hh < 7) {
        int base = cc * (OT * OH * OW) + hh * OW;
#pragma unroll
        for (int t = 0; t < OT; ++t)
#pragma unroll
            for (int w = 0; w < OW; ++w)
                scratch[base + t * (OH * OW) + w] = racc[t][w] * 0.125f;
    }
    __syncthreads();

    float* outb = out + ((size_t)r * C_ + c0) * (OT * OH * OW);
    for (int k = 0; k < (NOUT + 255) / 256; ++k) {
        int o = k * 256 + threadIdx.x;
        if (o < NOUT) __builtin_nontemporal_store(scratch[o], &outb[o]);
    }
}

// ---------------- fallback: direct gather, one thread per output ----------------
__device__ __forceinline__ void axis_sample(float start, float end, float size, int n,
                                            int j, int& lo_i, int& hi_i, float& frac,
                                            float& valid) {
    float length = fmaxf(end - start + 1.0f, 1.0f);
    float step = length / (float)(n - 1);
    float coord = start + step * (float)j;
    valid = (coord >= 0.0f && coord < size) ? 1.0f : 0.0f;
    float lo = fminf(fmaxf(floorf(coord), 0.0f), size - 1.0f);
    frac = coord - lo;
    lo_i = (int)lo;
    hi_i = min(lo_i + 1, (int)size - 1);
}

__global__ void roi_direct(const float* __restrict__ f, const float* __restrict__ rois,
                           float* __restrict__ out, long long total) {
    long long idx = (long long)blockIdx.x * 256 + threadIdx.x;
    if (idx >= total) return;
    int w = (int)(idx % OW);
    long long q = idx / OW;
    int h = (int)(q % OH);
    q /= OH;
    int t = (int)(q % OT);
    q /= OT;
    int c = (int)(q % C_);
    int r = (int)(q / C_);

    float rb = rois[r * 7 + 0];
    float x1 = rois[r * 7 + 1] * SSCALE;
    float y1 = rois[r * 7 + 2] * SSCALE;
    float x2 = rois[r * 7 + 3] * SSCALE;
    float y2 = rois[r * 7 + 4] * SSCALE;
    float t1 = rois[r * 7 + 5] * TSCALE;
    float t2 = rois[r * 7 + 6] * TSCALE;
    int b = (int)rb;
    const float* fc = f + ((size_t)b * C_ + c) * (T_ * H_ * W_);

    float acc = 0.0f;
    for (int dt = 0; dt < 2; ++dt) {
        int tlo, thi; float tf, tv;
        axis_sample(t1, t2, (float)T_, PT, t + dt, tlo, thi, tf, tv);
        for (int dh = 0; dh < 2; ++dh) {
            int ylo, yhi; float yf, yv;
            axis_sample(y1, y2, (float)H_, PH, h + dh, ylo, yhi, yf, yv);
            for (int dw = 0; dw < 2; ++dw) {
                int xlo, xhi; float xf, xv;
                axis_sample(x1, x2, (float)W_, PW, w + dw, xlo, xhi, xf, xv);
                float v000 = fc[(tlo * H_ + ylo) * W_ + xlo];
                float v001 = fc[(tlo * H_ + ylo) * W_ + xhi];
                float v010 = fc[(tlo * H_ + yhi) * W_ + xlo];
                float v011 = fc[(tlo * H_ + yhi) * W_ + xhi];
                float v100 = fc[(thi * H_ + ylo) * W_ + xlo];
                float v101 = fc[(thi * H_ + ylo) * W_ + xhi];
                float v110 = fc[(thi * H_ + yhi) * W_ + xlo];
                float v111 = fc[(thi * H_ + yhi) * W_ + xhi];
                float vx00 = v000 + xf * (v001 - v000);
                float vx01 = v010 + xf * (v011 - v010);
                float vx10 = v100 + xf * (v101 - v100);
                float vx11 = v110 + xf * (v111 - v110);
                float vy0 = vx00 + yf * (vx01 - vx00);
                float vy1 = vx10 + yf * (vx11 - vx10);
                float v = vy0 + tf * (vy1 - vy0);
                acc += v * (tv * yv * xv);
            }
        }
    }
    out[idx] = acc * 0.125f;
}

extern "C" void kernel_launch(void* const* d_in, const int* in_sizes, int n_in,
                              void* d_out, int out_size, void* d_ws, size_t ws_size,
                              hipStream_t stream) {
    const float* feat = (const float*)d_in[0];
    const float* rois = (const float*)d_in[1];
    float* out = (float*)d_out;
    int nroi = in_sizes[1] / 7;
    int B = in_sizes[0] / (C_ * T_ * H_ * W_);
    size_t need = (size_t)B * T_ * H_ * W_ * C_ * sizeof(float);

    if (ws_size >= need) {
        dim3 g1(T_ * H_ * W_ / 256, C_ / 64, B);
        transpose_kernel<<<g1, 256, 0, stream>>>(feat, (float*)d_ws);
        roi_kernel<<<dim3(nroi * (C_ / CG)), 256, 0, stream>>>((const float*)d_ws, rois, out);
    } else {
        long long total = (long long)nroi * C_ * OT * OH * OW;
        roi_direct<<<(int)((total + 255) / 256), 256, 0, stream>>>(feat, rois, out, total);
    }
}

// Round 4
// 573.501 us; speedup vs baseline: 1.6502x; 1.0924x over previous
//
#include <hip/hip_runtime.h>

#define C_ 256
#define T_ 16
#define H_ 64
#define W_ 64
#define PT 5
#define PH 8
#define PW 8
#define OT 4
#define OH 7
#define OW 7
#define SSCALE (1.0f/16.0f)
#define TSCALE 1.0f
#define CG 32               /* channels per roi block */
#define LROW 66             /* plane row stride: 8B-aligned, 2-way banks max */
#define NOUT (CG * OT * OH * OW)   /* 6272 outputs per block */

typedef float f4v __attribute__((ext_vector_type(4)));
typedef float f2v __attribute__((ext_vector_type(2)));
typedef _Float16 h4v __attribute__((ext_vector_type(4)));
typedef _Float16 h8v __attribute__((ext_vector_type(8)));

// ---------------- transpose+cvt (B,C,T,H,W) f32 -> (B,T,H,W,C) fp16 ----------------
__global__ __launch_bounds__(256) void transpose_kernel(const float* __restrict__ f,
                                                        _Float16* __restrict__ ft) {
    __shared__ float tile[64][65];
    const int THW = T_ * H_ * W_;
    int c0 = blockIdx.y * 64;
    int b = blockIdx.z;
    int l4 = threadIdx.x & 15;
    int row = threadIdx.x >> 4;
    for (int k4 = 0; k4 < 4; ++k4) {
        int thw0 = blockIdx.x * 256 + k4 * 64;
        if (k4) __syncthreads();
#pragma unroll
        for (int k = 0; k < 4; ++k) {
            int c = row + k * 16;
            const f4v* src = reinterpret_cast<const f4v*>(
                &f[((size_t)b * C_ + c0 + c) * THW + thw0 + l4 * 4]);
            f4v v = __builtin_nontemporal_load(src);  // f read once; keep L3 for ft
            tile[c][l4 * 4 + 0] = v[0];
            tile[c][l4 * 4 + 1] = v[1];
            tile[c][l4 * 4 + 2] = v[2];
            tile[c][l4 * 4 + 3] = v[3];
        }
        __syncthreads();
#pragma unroll
        for (int k = 0; k < 4; ++k) {
            int t = row + k * 16;
            h4v v;
            v[0] = (_Float16)tile[l4 * 4 + 0][t];
            v[1] = (_Float16)tile[l4 * 4 + 1][t];
            v[2] = (_Float16)tile[l4 * 4 + 2][t];
            v[3] = (_Float16)tile[l4 * 4 + 3][t];
            // normal (cached) store: ft should stay L3-resident for the gather
            *reinterpret_cast<h4v*>(&ft[((size_t)b * THW + thw0 + t) * C_ + c0 + l4 * 4]) = v;
        }
    }
}

// ---------------- main: one block per (roi, 32-channel group) ----------------
// fp16 ft gather (16B half8 taps, 8 ch/thread), t-plane streaming,
// register-accumulated pool, coalesced f4v flush.
__global__ __launch_bounds__(256) void roi_kernel(const _Float16* __restrict__ ft,
                                                  const float* __restrict__ rois,
                                                  float* __restrict__ out) {
    __shared__ float scratch[NOUT];  // 25088 B; first 2112 floats double as plane buffer
    __shared__ float sroi[7];
    __shared__ int2 s_trow[PT]; __shared__ float2 s_twt[PT];
    __shared__ int2 s_yrow[PH]; __shared__ float2 s_ywt[PH];
    __shared__ int2 s_xoff[PW]; __shared__ float2 s_xwt[PW];

    // natural decode: cg in low 3 bits -> round-robin puts each channel-slice
    // on its own XCD (per-XCD L2 working set = ft/8).
    int bid = blockIdx.x;
    int r = bid >> 3;
    int cg = bid & 7;
    int c0 = cg * CG;

    if (threadIdx.x < 7) sroi[threadIdx.x] = rois[r * 7 + threadIdx.x];
    __syncthreads();

    // axis tables: byte offsets (lo/hi) + validity-folded weights
    if (threadIdx.x < 21) {
        int i = threadIdx.x;
        float start, end, size;
        int j, n, scale;
        if (i < 5) {
            j = i; n = PT;
            start = sroi[5] * TSCALE; end = sroi[6] * TSCALE;
            size = (float)T_; scale = H_ * W_ * C_ * 2;
        } else if (i < 13) {
            j = i - 5; n = PH;
            start = sroi[2] * SSCALE; end = sroi[4] * SSCALE;
            size = (float)H_; scale = W_ * C_ * 2;
        } else {
            j = i - 13; n = PW;
            start = sroi[1] * SSCALE; end = sroi[3] * SSCALE;
            size = (float)W_; scale = C_ * 2;
        }
        float length = fmaxf(end - start + 1.0f, 1.0f);
        float step = length / (float)(n - 1);
        float coord = start + step * (float)j;
        float valid = (coord >= 0.0f && coord < size) ? 1.0f : 0.0f;
        float lo = fminf(fmaxf(floorf(coord), 0.0f), size - 1.0f);
        int lo_i = (int)lo;
        int hi_i = min(lo_i + 1, (int)size - 1);
        float fr = coord - lo;
        int2 offs; offs.x = lo_i * scale; offs.y = hi_i * scale;
        float2 wts; wts.x = (1.0f - fr) * valid; wts.y = fr * valid;
        if (i < 5)       { s_trow[j] = offs; s_twt[j] = wts; }
        else if (i < 13) { s_yrow[j] = offs; s_ywt[j] = wts; }
        else             { s_xoff[j] = offs; s_xwt[j] = wts; }
    }
    __syncthreads();

    int b = (int)sroi[0];
    int c4 = threadIdx.x & 3;     // half8 lane: 4 lanes x 8 ch = 32 channels
    int slot = threadIdx.x >> 2;  // 0..63 sample slot (full 8x8 plane in one pass)
    const char* fb = (const char*)ft
        + ((size_t)b * (T_ * H_ * W_ * C_) + (size_t)(c0 + c4 * 8)) * 2;

    float (*buf)[LROW] = (float(*)[LROW])scratch;  // 32 x 66 = 2112 floats
    int cc = threadIdx.x & 31;
    int hh = threadIdx.x >> 5;    // 0..7; hh==7 idle for pooling

    float racc[OT][OW];           // statically indexed (t-loop fully unrolled)
#pragma unroll
    for (int t = 0; t < OT; ++t)
#pragma unroll
        for (int w = 0; w < OW; ++w) racc[t][w] = 0.0f;

    int y = slot >> 3, x = slot & 7;
    int2 yr = s_yrow[y]; float2 yw = s_ywt[y];
    int2 xo = s_xoff[x]; float2 xw = s_xwt[x];

#pragma unroll
    for (int t = 0; t < PT; ++t) {
        if (t) __syncthreads();   // pool reads of plane t-1 done before overwrite

        // ---- compute plane t: 64 samples x 32 channels (8 ch/thread) ----
        int2 tr = s_trow[t];
        float2 tw = s_twt[t];
        int rA = tr.x + yr.x;
        int rB = tr.x + yr.y;
        int rC = tr.y + yr.x;
        int rD = tr.y + yr.y;
        float wA = tw.x * yw.x, wB = tw.x * yw.y;
        float wC = tw.y * yw.x, wD = tw.y * yw.y;

        f4v accL = {0.f, 0.f, 0.f, 0.f};
        f4v accH = {0.f, 0.f, 0.f, 0.f};
#pragma unroll
        for (int tap = 0; tap < 8; ++tap) {
            int ro = (tap & 1) ? ((tap >> 1) == 0 ? rA : (tap >> 1) == 1 ? rB
                                  : (tap >> 1) == 2 ? rC : rD) + xo.y
                               : ((tap >> 1) == 0 ? rA : (tap >> 1) == 1 ? rB
                                  : (tap >> 1) == 2 ? rC : rD) + xo.x;
            float w = ((tap >> 1) == 0 ? wA : (tap >> 1) == 1 ? wB
                       : (tap >> 1) == 2 ? wC : wD) * ((tap & 1) ? xw.y : xw.x);
            h8v h = *(const h8v*)(fb + ro);
            f4v lo = {(float)h[0], (float)h[1], (float)h[2], (float)h[3]};
            f4v hi = {(float)h[4], (float)h[5], (float)h[6], (float)h[7]};
            accL += w * lo;
            accH += w * hi;
        }
        {
            float* col = &buf[c4 * 8][slot];
            col[0 * LROW] = accL[0];
            col[1 * LROW] = accL[1];
            col[2 * LROW] = accL[2];
            col[3 * LROW] = accL[3];
            col[4 * LROW] = accH[0];
            col[5 * LROW] = accH[1];
            col[6 * LROW] = accH[2];
            col[7 * LROW] = accH[3];
        }
        __syncthreads();

        // ---- accumulate plane t into racc[t] (dt=0) and racc[t-1] (dt=1) ----
        if (hh < 7) {
            const float* p = &buf[cc][hh * 8];
            float p2[8];
#pragma unroll
            for (int x2 = 0; x2 < 4; ++x2) {
                f2v a = *(const f2v*)(p + 2 * x2);
                f2v bq = *(const f2v*)(p + 8 + 2 * x2);
                f2v s = a + bq;           // y-pool (rows hh, hh+1)
                p2[2 * x2] = s[0];
                p2[2 * x2 + 1] = s[1];
            }
#pragma unroll
            for (int w = 0; w < OW; ++w) {
                float pw = p2[w] + p2[w + 1];   // x-pool
                if (t < OT) racc[t][w] += pw;
                if (t > 0) racc[t - 1][w] += pw;
            }
        }
    }
    __syncthreads();  // plane buffer dead; scratch reused for flush

    // ---- stage pooled outputs in (c,t,h,w) order, flush coalesced ----
    if (hh < 7) {
        int base = cc * (OT * OH * OW) + hh * OW;
#pragma unroll
        for (int t = 0; t < OT; ++t)
#pragma unroll
            for (int w = 0; w < OW; ++w)
                scratch[base + t * (OH * OW) + w] = racc[t][w] * 0.125f;
    }
    __syncthreads();

    float* outb = out + ((size_t)r * C_ + c0) * (OT * OH * OW);
    const f4v* s4 = (const f4v*)scratch;
    f4v* o4 = (f4v*)outb;
    for (int k = 0; k < 7; ++k) {
        int idx = k * 256 + threadIdx.x;
        if (idx < NOUT / 4) __builtin_nontemporal_store(s4[idx], &o4[idx]);
    }
}

// ---------------- fallback: direct gather, one thread per output ----------------
__device__ __forceinline__ void axis_sample(float start, float end, float size, int n,
                                            int j, int& lo_i, int& hi_i, float& frac,
                                            float& valid) {
    float length = fmaxf(end - start + 1.0f, 1.0f);
    float step = length / (float)(n - 1);
    float coord = start + step * (float)j;
    valid = (coord >= 0.0f && coord < size) ? 1.0f : 0.0f;
    float lo = fminf(fmaxf(floorf(coord), 0.0f), size - 1.0f);
    frac = coord - lo;
    lo_i = (int)lo;
    hi_i = min(lo_i + 1, (int)size - 1);
}

__global__ void roi_direct(const float* __restrict__ f, const float* __restrict__ rois,
                           float* __restrict__ out, long long total) {
    long long idx = (long long)blockIdx.x * 256 + threadIdx.x;
    if (idx >= total) return;
    int w = (int)(idx % OW);
    long long q = idx / OW;
    int h = (int)(q % OH);
    q /= OH;
    int t = (int)(q % OT);
    q /= OT;
    int c = (int)(q % C_);
    int r = (int)(q / C_);

    float rb = rois[r * 7 + 0];
    float x1 = rois[r * 7 + 1] * SSCALE;
    float y1 = rois[r * 7 + 2] * SSCALE;
    float x2 = rois[r * 7 + 3] * SSCALE;
    float y2 = rois[r * 7 + 4] * SSCALE;
    float t1 = rois[r * 7 + 5] * TSCALE;
    float t2 = rois[r * 7 + 6] * TSCALE;
    int b = (int)rb;
    const float* fc = f + ((size_t)b * C_ + c) * (T_ * H_ * W_);

    float acc = 0.0f;
    for (int dt = 0; dt < 2; ++dt) {
        int tlo, thi; float tf, tv;
        axis_sample(t1, t2, (float)T_, PT, t + dt, tlo, thi, tf, tv);
        for (int dh = 0; dh < 2; ++dh) {
            int ylo, yhi; float yf, yv;
            axis_sample(y1, y2, (float)H_, PH, h + dh, ylo, yhi, yf, yv);
            for (int dw = 0; dw < 2; ++dw) {
                int xlo, xhi; float xf, xv;
                axis_sample(x1, x2, (float)W_, PW, w + dw, xlo, xhi, xf, xv);
                float v000 = fc[(tlo * H_ + ylo) * W_ + xlo];
                float v001 = fc[(tlo * H_ + ylo) * W_ + xhi];
                float v010 = fc[(tlo * H_ + yhi) * W_ + xlo];
                float v011 = fc[(tlo * H_ + yhi) * W_ + xhi];
                float v100 = fc[(thi * H_ + ylo) * W_ + xlo];
                float v101 = fc[(thi * H_ + ylo) * W_ + xhi];
                float v110 = fc[(thi * H_ + yhi) * W_ + xlo];
                float v111 = fc[(thi * H_ + yhi) * W_ + xhi];
                float vx00 = v000 + xf * (v001 - v000);
                float vx01 = v010 + xf * (v011 - v010);
                float vx10 = v100 + xf * (v101 - v100);
                float vx11 = v110 + xf * (v111 - v110);
                float vy0 = vx00 + yf * (vx01 - vx00);
                float vy1 = vx10 + yf * (vx11 - vx10);
                float v = vy0 + tf * (vy1 - vy0);
                acc += v * (tv * yv * xv);
            }
        }
    }
    out[idx] = acc * 0.125f;
}

extern "C" void kernel_launch(void* const* d_in, const int* in_sizes, int n_in,
                              void* d_out, int out_size, void* d_ws, size_t ws_size,
                              hipStream_t stream) {
    const float* feat = (const float*)d_in[0];
    const float* rois = (const float*)d_in[1];
    float* out = (float*)d_out;
    int nroi = in_sizes[1] / 7;
    int B = in_sizes[0] / (C_ * T_ * H_ * W_);
    size_t need = (size_t)B * T_ * H_ * W_ * C_ * sizeof(_Float16);

    if (ws_size >= need) {
        dim3 g1(T_ * H_ * W_ / 256, C_ / 64, B);
        transpose_kernel<<<g1, 256, 0, stream>>>(feat, (_Float16*)d_ws);
        roi_kernel<<<dim3(nroi * (C_ / CG)), 256, 0, stream>>>((const _Float16*)d_ws, rois, out);
    } else {
        long long total = (long long)nroi * C_ * OT * OH * OW;
        roi_direct<<<(int)((total + 255) / 256), 256, 0, stream>>>(feat, rois, out, total);
    }
}